// Round 5
// baseline (461.648 us; speedup 1.0000x reference)
//
#include <hip/hip_runtime.h>
#include <hip/hip_bf16.h>
#include <cstdint>

// Problem constants (from reference): B=64 graphs, N=512 nodes, H=1024 hidden, E=4 experts.
constexpr int Bc = 64, Nc = 512, Hc = 1024, Ec = 4;
constexpr float EPS = 1e-5f;

typedef __attribute__((ext_vector_type(8))) short bf16x8;
typedef __attribute__((ext_vector_type(4))) float f32x4;
typedef __attribute__((ext_vector_type(4))) unsigned short us4;

__device__ __forceinline__ unsigned short f2b(float f) {
  union { float f; unsigned u; } v; v.f = f;
  unsigned r = v.u + 0x7fffu + ((v.u >> 16) & 1u);   // RNE
  return (unsigned short)(r >> 16);
}
__device__ __forceinline__ float b2f(unsigned short s) {
  union { unsigned u; float f; } v; v.u = ((unsigned)s) << 16;
  return v.f;
}

// ---------------- x: fp32 -> bf16, plus per-(b,h) sums for router mean ----------------
__global__ void k_xconv(const float* __restrict__ x, unsigned short* __restrict__ xb,
                        float* __restrict__ xm) {
  const int b = blockIdx.x >> 3;
  const int n0 = (blockIdx.x & 7) << 6;
  const int t = threadIdx.x;
  size_t base = ((size_t)b * Nc + n0) * Hc + t * 4;
  float s0 = 0.f, s1 = 0.f, s2 = 0.f, s3 = 0.f;
  for (int i = 0; i < 64; ++i) {
    float4 v = *(const float4*)(x + base + (size_t)i * Hc);
    us4 u; u.x = f2b(v.x); u.y = f2b(v.y); u.z = f2b(v.z); u.w = f2b(v.w);
    *(us4*)(xb + base + (size_t)i * Hc) = u;
    s0 += v.x; s1 += v.y; s2 += v.z; s3 += v.w;
  }
  float* p = xm + b * Hc + t * 4;
  atomicAdd(p + 0, s0); atomicAdd(p + 1, s1);
  atomicAdd(p + 2, s2); atomicAdd(p + 3, s3);
}

// ---------------- adj: fp32 -> bf16 ----------------
__global__ void k_adjconv(const float* __restrict__ a, unsigned short* __restrict__ ab) {
  size_t i = ((size_t)blockIdx.x * 256 + threadIdx.x) * 4;
  float4 v = *(const float4*)(a + i);
  us4 u; u.x = f2b(v.x); u.y = f2b(v.y); u.z = f2b(v.z); u.w = f2b(v.w);
  *(us4*)(ab + i) = u;
}

// ---------------- expert_w: fp32 -> bf16 transposed: wT[e][k][h] = w[e][h][k] ----------------
__global__ void k_wtrans(const float* __restrict__ w, unsigned short* __restrict__ wT) {
  __shared__ unsigned short tile[32][33];
  const int e = blockIdx.z;
  const int bx = blockIdx.x * 32;
  const int by = blockIdx.y * 32;
  const float* W = w + (size_t)e * Hc * Hc;
  unsigned short* WT = wT + (size_t)e * Hc * Hc;
#pragma unroll
  for (int i = 0; i < 4; ++i) {
    int r = by + threadIdx.y + i * 8;
    tile[threadIdx.y + i * 8][threadIdx.x] = f2b(W[(size_t)r * Hc + bx + threadIdx.x]);
  }
  __syncthreads();
#pragma unroll
  for (int i = 0; i < 4; ++i) {
    int k = bx + threadIdx.y + i * 8;
    WT[(size_t)k * Hc + by + threadIdx.x] = tile[threadIdx.x][threadIdx.y + i * 8];
  }
}

// ---------------- router: scores + argmax ----------------
__global__ void k_router(const float* __restrict__ xm, const float* __restrict__ rw,
                         const float* __restrict__ rb, int* __restrict__ top1) {
  const int b = blockIdx.x;
  const int t = threadIdx.x;
  float sc0 = 0, sc1 = 0, sc2 = 0, sc3 = 0;
  const float inv = 1.0f / (float)Nc;
#pragma unroll
  for (int i = 0; i < 4; ++i) {
    int h = t * 4 + i;
    float v = xm[b * Hc + h] * inv;
    sc0 += v * rw[h * 4 + 0]; sc1 += v * rw[h * 4 + 1];
    sc2 += v * rw[h * 4 + 2]; sc3 += v * rw[h * 4 + 3];
  }
#pragma unroll
  for (int off = 1; off < 64; off <<= 1) {
    sc0 += __shfl_xor(sc0, off); sc1 += __shfl_xor(sc1, off);
    sc2 += __shfl_xor(sc2, off); sc3 += __shfl_xor(sc3, off);
  }
  __shared__ float red[4][4];
  const int lane = t & 63, wv = t >> 6;
  if (lane == 0) { red[wv][0] = sc0; red[wv][1] = sc1; red[wv][2] = sc2; red[wv][3] = sc3; }
  __syncthreads();
  if (t == 0) {
    float s[4];
#pragma unroll
    for (int e = 0; e < 4; ++e)
      s[e] = red[0][e] + red[1][e] + red[2][e] + red[3][e] + rb[e];
    int best = 0; float bv = s[0];
#pragma unroll
    for (int e = 1; e < 4; ++e) { if (s[e] > bv) { bv = s[e]; best = e; } }
    top1[b] = best;
  }
}

// ============ 256x256 triple-buffered MFMA GEMM: C[M,Nn] = A[M,K] * Bt[Nn,K]^T ============
// BM=BN=256, BK=32, 8 waves (2M x 4N), per-wave 128x64 output, 16x16x32 bf16 MFMA.
// 3 LDS buffers (96 KiB): stage tile kt+2 at top of tile kt; ONE s_barrier + ONE counted
// vmcnt(4) per K-tile (issue-to-wait distance = 2 tiles). ds_read<->MFMA interleave left
// to the compiler's counted lgkmcnt. Row-XOR chunk swizzle (both sides), XCD block swizzle.
#define GLDS16(g, l) __builtin_amdgcn_global_load_lds( \
    (__attribute__((address_space(1))) const void*)(g), \
    (__attribute__((address_space(3))) void*)(l), 16, 0, 0)

template<int NX, int NY, bool STATS>
__global__ __launch_bounds__(512, 2) void gemm3(
    const unsigned short* __restrict__ Aall, const unsigned short* __restrict__ Btall,
    unsigned short* __restrict__ Call, const int* __restrict__ top1,
    float* __restrict__ ssum, float* __restrict__ ssq,
    int Nn, int K, long aPerB, long btPerB, long cPerB, long aExp)
{
  static_assert(NX * NY == 8, "grid per graph must be 8 blocks");
  __shared__ char Lds[98304];                    // 3 bufs x 32 KiB
#define AB(b) (Lds + (b) * 32768)                //   A: 2 halves x 8 KiB (128 rows x 32 cols)
#define BB(b) (Lds + (b) * 32768 + 16384)        //   B: 2 halves x 8 KiB

  const int tid = threadIdx.x;
  const int w = tid >> 6, lane = tid & 63;
  const int wm = w >> 2, wn = w & 3;
  const int fr = lane & 15, fq = lane >> 4;

  // XCD-aware bijective block swizzle: 64 consecutive blocks (8 graphs) per XCD chunk.
  const int id = blockIdx.x;
  const int s = (id & 7) * (NX * NY * 8) + (id >> 3);
  const int bz = s >> 3;
  const int r = s & 7;
  const int bx = r % NX, by = r / NX;
  const int m0 = bx * 256, n0 = by * 256;

  const unsigned short* Ag = Aall + (aExp ? (long)top1[bz] * aExp : (long)bz * aPerB);
  const unsigned short* Bg = Btall + (long)bz * btPerB;

  // staging: thread t covers 16B chunk c=tid of a 128x32 half-tile:
  // row = tid>>2 (0..127), lds-chunk = tid&3, global chunk pre-swizzled g=(tid&3)^(row&3)
  // so lds(row, cc) holds global chunk cc^(row&3)  [both-sides swizzle].
  const int srow = tid >> 2;
  const int g8 = ((tid & 3) ^ (srow & 3)) * 8;   // element offset within BK=32
  const int wb16 = w << 10;                      // wave-uniform LDS base (w*64*16B)
  const unsigned short* aR0 = Ag + (size_t)(m0 + srow) * K + g8;
  const unsigned short* aR1 = Ag + (size_t)(m0 + 128 + srow) * K + g8;
  const unsigned short* bR0 = Bg + (size_t)(n0 + srow) * K + g8;
  const unsigned short* bR1 = Bg + (size_t)(n0 + 128 + srow) * K + g8;
#define STAGE_TILE(b, kc) do { \
    GLDS16(aR0 + (kc), AB(b) + wb16); \
    GLDS16(aR1 + (kc), AB(b) + 8192 + wb16); \
    GLDS16(bR0 + (kc), BB(b) + wb16); \
    GLDS16(bR1 + (kc), BB(b) + 8192 + wb16); \
  } while (0)

  // fragment read: row-in-half r at logical chunk fq -> byte r*64 + ((fq^(r&3))*16); r&3==fr&3
  const int cOff = (fq ^ (fr & 3)) * 16;
  const int bRow0 = (wn & 1) * 64 + fr;          // B row within its half

  f32x4 acc[8][4] = {};
  const int NT = K >> 5;

  // ---- prologue: stage tiles 0 and 1; land tile 0, keep tile 1 in flight
  STAGE_TILE(0, 0);
  STAGE_TILE(1, 32);
  asm volatile("s_waitcnt vmcnt(4)" ::: "memory");
  __builtin_amdgcn_s_barrier();

  for (int kt = 0; kt < NT; ++kt) {
    const int bsel = kt % 3;
    if (kt + 2 < NT) STAGE_TILE((kt + 2) % 3, (kt + 2) << 5);

    const char* aH = AB(bsel) + wm * 8192;
    const char* bH = BB(bsel) + (wn >> 1) * 8192;
    bf16x8 Af[8], Bf[4];
#pragma unroll
    for (int mi = 0; mi < 8; ++mi)
      Af[mi] = *(const bf16x8*)(aH + (mi * 16 + fr) * 64 + cOff);
#pragma unroll
    for (int ni = 0; ni < 4; ++ni)
      Bf[ni] = *(const bf16x8*)(bH + (bRow0 + ni * 16) * 64 + cOff);

    __builtin_amdgcn_s_setprio(1);
#pragma unroll
    for (int mi = 0; mi < 8; ++mi)
#pragma unroll
      for (int ni = 0; ni < 4; ++ni)
        acc[mi][ni] = __builtin_amdgcn_mfma_f32_16x16x32_bf16(Af[mi], Bf[ni], acc[mi][ni], 0, 0, 0);
    __builtin_amdgcn_s_setprio(0);

    // counted drain: outstanding = {kt+1: 4, kt+2: 4}; vmcnt(4) lands tile kt+1 exactly.
    if (kt < NT - 2)       { asm volatile("s_waitcnt vmcnt(4)" ::: "memory"); }
    else if (kt == NT - 2) { asm volatile("s_waitcnt vmcnt(0)" ::: "memory"); }
    if (kt < NT - 1) __builtin_amdgcn_s_barrier();
  }

  // ---- epilogue: C[row][col] bf16; row = m0+wm*128+mi*16+fq*4+j, col = n0+wn*64+ni*16+fr
  unsigned short* Cg = Call + (long)bz * cPerB;
  const int colBase = n0 + wn * 64 + fr;
  const int rowBase = m0 + wm * 128 + fq * 4;
#pragma unroll
  for (int mi = 0; mi < 8; ++mi)
#pragma unroll
    for (int ni = 0; ni < 4; ++ni) {
      const int col = colBase + ni * 16;
      const int rw = rowBase + mi * 16;
#pragma unroll
      for (int j = 0; j < 4; ++j)
        Cg[(size_t)(rw + j) * Nn + col] = f2b(acc[mi][ni][j]);
    }

  if (STATS) {
    const int e = top1[bz];
#pragma unroll
    for (int ni = 0; ni < 4; ++ni) {
      float s1 = 0.f, s2 = 0.f;
#pragma unroll
      for (int mi = 0; mi < 8; ++mi)
#pragma unroll
        for (int j = 0; j < 4; ++j) { float v = acc[mi][ni][j]; s1 += v; s2 += v * v; }
      s1 += __shfl_xor(s1, 16); s2 += __shfl_xor(s2, 16);
      s1 += __shfl_xor(s1, 32); s2 += __shfl_xor(s2, 32);
      if (fq == 0) {
        const int col = colBase + ni * 16;
        atomicAdd(&ssum[e * Hc + col], s1);
        atomicAdd(&ssq[e * Hc + col], s2);
      }
    }
  }
#undef STAGE_TILE
#undef AB
#undef BB
}

// ---------------- BN finalize: scale/shift per [E,H] ----------------
__global__ void k_bnfin(const float* __restrict__ ssum, const float* __restrict__ ssq,
                        const int* __restrict__ top1,
                        const float* __restrict__ gamma, const float* __restrict__ beta,
                        float* __restrict__ scale, float* __restrict__ shift) {
  const int i = blockIdx.x * 256 + threadIdx.x;  // E*H = 4096
  const int e = i >> 10;
  int c = 0;
  for (int j = 0; j < Bc; ++j) c += (top1[j] == e) ? 1 : 0;
  float cf = fmaxf((float)c * (float)Nc, 1.0f);
  float mean = ssum[i] / cf;
  float var = ssq[i] / cf - mean * mean;
  float inv = rsqrtf(var + EPS);
  float sc = gamma[i] * inv;
  scale[i] = sc;
  shift[i] = beta[i] - mean * sc;
}

// ---------------- apply BN + ReLU, bf16 -> fp32 out ----------------
__global__ void k_apply(const unsigned short* __restrict__ ob,
                        const float* __restrict__ scale, const float* __restrict__ shift,
                        const int* __restrict__ top1, float* __restrict__ y) {
  size_t idx = ((size_t)blockIdx.x * 256 + threadIdx.x) * 4;
  const int b = (int)(idx >> 19);     // N*H = 2^19
  const int k = (int)(idx & 1023);    // H = 1024
  const int e = top1[b];
  us4 u = *(const us4*)(ob + idx);
  float4 sc = *(const float4*)(scale + e * Hc + k);
  float4 sh = *(const float4*)(shift + e * Hc + k);
  float4 r;
  r.x = fmaxf(fmaf(b2f(u.x), sc.x, sh.x), 0.f);
  r.y = fmaxf(fmaf(b2f(u.y), sc.y, sh.y), 0.f);
  r.z = fmaxf(fmaf(b2f(u.z), sc.z, sh.z), 0.f);
  r.w = fmaxf(fmaf(b2f(u.w), sc.w, sh.w), 0.f);
  *(float4*)(y + idx) = r;
}

extern "C" void kernel_launch(void* const* d_in, const int* in_sizes, int n_in,
                              void* d_out, int out_size, void* d_ws, size_t ws_size,
                              hipStream_t stream) {
  const float* x     = (const float*)d_in[0];
  const float* adj   = (const float*)d_in[1];
  const float* rw    = (const float*)d_in[2];
  const float* rb    = (const float*)d_in[3];
  const float* ew    = (const float*)d_in[4];
  const float* gamma = (const float*)d_in[5];
  const float* beta  = (const float*)d_in[6];
  float* out = (float*)d_out;
  char* ws = (char*)d_ws;

  // workspace layout (bytes)
  float* xm    = (float*)(ws + 0);          // 262144
  float* ssum  = (float*)(ws + 262144);     // 16384
  float* ssq   = (float*)(ws + 278528);     // 16384
  float* scale = (float*)(ws + 294912);     // 16384
  float* shift = (float*)(ws + 311296);     // 16384
  int*   top1  = (int*)  (ws + 327680);     // 256
  unsigned short* xb   = (unsigned short*)(ws + 327936);     // 67108864 (aliased by outb)
  unsigned short* adjb = (unsigned short*)(ws + 67436800);   // 33554432
  unsigned short* wT   = (unsigned short*)(ws + 100991232);  // 8388608
  unsigned short* supT = (unsigned short*)(ws + 109379840);  // 67108864
  unsigned short* outb = xb;  // x_bf16 dead after GEMM1 -> reuse for out_bf16

  hipMemsetAsync(ws, 0, 294912, stream);  // zero xm + ssum + ssq

  k_xconv<<<Bc * 8, 256, 0, stream>>>(x, xb, xm);
  k_adjconv<<<(Bc * Nc * Nc) / 1024, 256, 0, stream>>>(adj, adjb);
  k_wtrans<<<dim3(Hc / 32, Hc / 32, Ec), dim3(32, 8), 0, stream>>>(ew, wT);
  k_router<<<Bc, 256, 0, stream>>>(xm, rw, rb, top1);

  // GEMM1: supT[b][k][n] = sum_h wT[e][k][h] * x[b][n][h];  M=1024 (NX=4), Nn=512 (NY=2), K=1024
  gemm3<4, 2, false><<<512, 512, 0, stream>>>(
      wT, xb, supT, top1, nullptr, nullptr,
      Nc, Hc, 0L, (long)Nc * Hc, (long)Hc * Nc, (long)Hc * Hc);

  // GEMM2: out[b][n][k] = sum_m adj[b][n][m] * supT[b][k][m];  M=512 (NX=2), Nn=1024 (NY=4), K=512
  gemm3<2, 4, true><<<512, 512, 0, stream>>>(
      adjb, supT, outb, top1, ssum, ssq,
      Hc, Nc, (long)Nc * Nc, (long)Hc * Nc, (long)Nc * Hc, 0L);

  k_bnfin<<<(Ec * Hc) / 256, 256, 0, stream>>>(ssum, ssq, top1, gamma, beta, scale, shift);
  k_apply<<<(Bc * Nc * Hc) / 1024, 256, 0, stream>>>(outb, scale, shift, top1, out);
}

// Round 7
// 455.248 us; speedup vs baseline: 1.0141x; 1.0141x over previous
//
#include <hip/hip_runtime.h>
#include <hip/hip_bf16.h>
#include <cstdint>

// Problem constants (from reference): B=64 graphs, N=512 nodes, H=1024 hidden, E=4 experts.
constexpr int Bc = 64, Nc = 512, Hc = 1024, Ec = 4;
constexpr float EPS = 1e-5f;

typedef __attribute__((ext_vector_type(8))) short bf16x8;
typedef __attribute__((ext_vector_type(4))) float f32x4;
typedef __attribute__((ext_vector_type(4))) unsigned short us4;

__device__ __forceinline__ unsigned short f2b(float f) {
  union { float f; unsigned u; } v; v.f = f;
  unsigned r = v.u + 0x7fffu + ((v.u >> 16) & 1u);   // RNE
  return (unsigned short)(r >> 16);
}
__device__ __forceinline__ float b2f(unsigned short s) {
  union { unsigned u; float f; } v; v.u = ((unsigned)s) << 16;
  return v.f;
}

// ---------------- x: fp32 -> bf16, plus per-(b,h) sums for router mean ----------------
// grid: Bc*16 blocks, 256 thr. Block = (graph b, 32 rows); unroll 4 keeps 4 loads in flight.
__global__ void k_xconv(const float* __restrict__ x, unsigned short* __restrict__ xb,
                        float* __restrict__ xm) {
  const int b = blockIdx.x >> 4;
  const int n0 = (blockIdx.x & 15) << 5;
  const int t = threadIdx.x;
  size_t base = ((size_t)b * Nc + n0) * Hc + t * 4;
  float s0 = 0.f, s1 = 0.f, s2 = 0.f, s3 = 0.f;
#pragma unroll 4
  for (int i = 0; i < 32; ++i) {
    float4 v = *(const float4*)(x + base + (size_t)i * Hc);
    us4 u; u.x = f2b(v.x); u.y = f2b(v.y); u.z = f2b(v.z); u.w = f2b(v.w);
    *(us4*)(xb + base + (size_t)i * Hc) = u;
    s0 += v.x; s1 += v.y; s2 += v.z; s3 += v.w;
  }
  float* p = xm + b * Hc + t * 4;
  atomicAdd(p + 0, s0); atomicAdd(p + 1, s1);
  atomicAdd(p + 2, s2); atomicAdd(p + 3, s3);
}

// ---------------- adj: fp32 -> bf16 ----------------
__global__ void k_adjconv(const float* __restrict__ a, unsigned short* __restrict__ ab) {
  size_t i = ((size_t)blockIdx.x * 256 + threadIdx.x) * 4;
  float4 v = *(const float4*)(a + i);
  us4 u; u.x = f2b(v.x); u.y = f2b(v.y); u.z = f2b(v.z); u.w = f2b(v.w);
  *(us4*)(ab + i) = u;
}

// ---------------- expert_w: fp32 -> bf16 transposed: wT[e][k][h] = w[e][h][k] ----------------
__global__ void k_wtrans(const float* __restrict__ w, unsigned short* __restrict__ wT) {
  __shared__ unsigned short tile[32][33];
  const int e = blockIdx.z;
  const int bx = blockIdx.x * 32;
  const int by = blockIdx.y * 32;
  const float* W = w + (size_t)e * Hc * Hc;
  unsigned short* WT = wT + (size_t)e * Hc * Hc;
#pragma unroll
  for (int i = 0; i < 4; ++i) {
    int r = by + threadIdx.y + i * 8;
    tile[threadIdx.y + i * 8][threadIdx.x] = f2b(W[(size_t)r * Hc + bx + threadIdx.x]);
  }
  __syncthreads();
#pragma unroll
  for (int i = 0; i < 4; ++i) {
    int k = bx + threadIdx.y + i * 8;
    WT[(size_t)k * Hc + by + threadIdx.x] = tile[threadIdx.x][threadIdx.y + i * 8];
  }
}

// ---------------- router: scores + argmax ----------------
__global__ void k_router(const float* __restrict__ xm, const float* __restrict__ rw,
                         const float* __restrict__ rb, int* __restrict__ top1) {
  const int b = blockIdx.x;
  const int t = threadIdx.x;
  float sc0 = 0, sc1 = 0, sc2 = 0, sc3 = 0;
  const float inv = 1.0f / (float)Nc;
#pragma unroll
  for (int i = 0; i < 4; ++i) {
    int h = t * 4 + i;
    float v = xm[b * Hc + h] * inv;
    sc0 += v * rw[h * 4 + 0]; sc1 += v * rw[h * 4 + 1];
    sc2 += v * rw[h * 4 + 2]; sc3 += v * rw[h * 4 + 3];
  }
#pragma unroll
  for (int off = 1; off < 64; off <<= 1) {
    sc0 += __shfl_xor(sc0, off); sc1 += __shfl_xor(sc1, off);
    sc2 += __shfl_xor(sc2, off); sc3 += __shfl_xor(sc3, off);
  }
  __shared__ float red[4][4];
  const int lane = t & 63, wv = t >> 6;
  if (lane == 0) { red[wv][0] = sc0; red[wv][1] = sc1; red[wv][2] = sc2; red[wv][3] = sc3; }
  __syncthreads();
  if (t == 0) {
    float s[4];
#pragma unroll
    for (int e = 0; e < 4; ++e)
      s[e] = red[0][e] + red[1][e] + red[2][e] + red[3][e] + rb[e];
    int best = 0; float bv = s[0];
#pragma unroll
    for (int e = 1; e < 4; ++e) { if (s[e] > bv) { bv = s[e]; best = e; } }
    top1[b] = best;
  }
}

// ========== 256x256 2-phase-per-tile MFMA GEMM: C[M,Nn] = A[M,K] * Bt[Nn,K]^T ==========
// BM=BN=256, BK=64, 8 waves (2M x 4N), per-wave 128x64, 16x16x32 bf16 MFMA.
// gemm8 layout/ledger (0 bank conflicts) with phases merged 4->2 per K-tile:
//   phase A: stage B(kt+1); read Af[0..7]+Bf[0..1]; 32 MFMA (ni 0..1)
//   phase B: stage A(kt+2); read Bf[2..3]; 32 MFMA (ni 2..3); counted vmcnt(4); barrier
// In-flight ledger (induction): at tile kt start = {A(kt+1):4}; phase A adds B(kt+1),
// phase B adds A(kt+2) -> 12; vmcnt(4) drains A(kt+1)+B(kt+1) before boundary barrier.
#define GLDS16(g, l) __builtin_amdgcn_global_load_lds( \
    (__attribute__((address_space(1))) const void*)(g), \
    (__attribute__((address_space(3))) void*)(l), 16, 0, 0)

#define PRE_MFMA() do { \
    __builtin_amdgcn_s_barrier(); \
    asm volatile("s_waitcnt lgkmcnt(0)" ::: "memory"); \
    __builtin_amdgcn_sched_barrier(0); \
    __builtin_amdgcn_s_setprio(1); \
  } while (0)
#define POST_MFMA() do { \
    __builtin_amdgcn_s_setprio(0); \
    __builtin_amdgcn_s_barrier(); \
    __builtin_amdgcn_sched_barrier(0); \
  } while (0)

template<int NX, int NY, bool STATS>
__global__ __launch_bounds__(512, 2) void gemm9(
    const unsigned short* __restrict__ Aall, const unsigned short* __restrict__ Btall,
    unsigned short* __restrict__ Call, const int* __restrict__ top1,
    float* __restrict__ ssum, float* __restrict__ ssq,
    int Nn, int K, long aPerB, long btPerB, long cPerB, long aExp)
{
  static_assert(NX * NY == 8, "grid per graph must be 8 blocks");
  __shared__ char Lds[131072];
#define ALDS(b, h) (Lds + (b) * 65536 + (h) * 16384)
#define BLDS(b, h) (Lds + (b) * 65536 + 32768 + (h) * 16384)

  const int tid = threadIdx.x;
  const int w = tid >> 6, lane = tid & 63;
  const int wm = w >> 2, wn = w & 3;
  const int fr = lane & 15, fq = lane >> 4;

  // XCD-aware bijective block swizzle: 64 consecutive blocks (8 graphs) per XCD chunk.
  const int id = blockIdx.x;
  const int s = (id & 7) * (NX * NY * 8) + (id >> 3);
  const int bz = s >> 3;
  const int r = s & 7;
  const int bx = r % NX, by = r / NX;
  const int m0 = bx * 256, n0 = by * 256;

  const unsigned short* Ag = Aall + (aExp ? (long)top1[bz] * aExp : (long)bz * aPerB);
  const unsigned short* Bg = Btall + (long)bz * btPerB;

  const unsigned short* As0 = Ag + (size_t)m0 * K;
  const unsigned short* As1 = Ag + (size_t)(m0 + 128) * K;
  const unsigned short* Bs0 = Bg + (size_t)n0 * K;
  const unsigned short* Bs1 = Bg + (size_t)(n0 + 128) * K;

  // staging: thread t covers lds 16B-chunks c=tid and c=tid+512 of a 128x64 half-tile
  // (row = c>>3, lds-chunk = c&7). Global source chunk pre-swizzled: g = (c&7)^(row&7)
  // so that lds(row, cc) holds global chunk cc^(row&7)  [both-sides swizzle].
  const int rowA = tid >> 3;                       // 0..63 (2nd GLDS16 covers rowA+64; same &7)
  const int g8 = ((tid & 7) ^ (rowA & 7)) * 8;     // element offset within BK
  const int wb = w << 10;                          // wave-uniform LDS base (w*64*16B)
#define STAGE(slot, src) do { \
    GLDS16((src) + (size_t)rowA * K + g8, (slot) + wb); \
    GLDS16((src) + (size_t)(rowA + 64) * K + g8, (slot) + wb + 8192); \
  } while (0)

  // fragment read addressing: logical chunk kc at byte row*128 + (kc^(row&7))*16
  const int cOff0 = ((fq ^ (fr & 7)) * 16);
  const int cOff1 = cOff0 ^ 64;
  const int bRow0 = (wn & 1) * 64 + fr;            // B row within half (row&7 == fr&7)

  f32x4 acc[8][4] = {};
  const int NT = K >> 6;

  // ---- prologue: tile0 (4 half-tiles) + tile1 A halves; land tile0, keep A(1) in flight
  STAGE(ALDS(0, 0), As0);
  STAGE(ALDS(0, 1), As1);
  STAGE(BLDS(0, 0), Bs0);
  STAGE(BLDS(0, 1), Bs1);
  STAGE(ALDS(1, 0), As0 + 64);
  STAGE(ALDS(1, 1), As1 + 64);
  asm volatile("s_waitcnt vmcnt(4)" ::: "memory");
  __builtin_amdgcn_s_barrier();
  __builtin_amdgcn_sched_barrier(0);

  for (int kt = 0; kt < NT; ++kt) {
    const int bsel = kt & 1;
    const int b1 = bsel ^ 1;                 // buffer of tile kt+1
    const char* aH = ALDS(bsel, wm);
    const char* bH = BLDS(bsel, wn >> 1);
    const int k1 = (kt + 1) << 6, k2 = (kt + 2) << 6;
    bf16x8 Af[8][2]; bf16x8 Bf[4][2];

    // ---- phase A: stage B(kt+1); read all Af + Bf[0..1]; MFMA (ni 0..1)
    if (kt + 1 < NT) { STAGE(BLDS(b1, 0), Bs0 + k1); STAGE(BLDS(b1, 1), Bs1 + k1); }
#pragma unroll
    for (int mi = 0; mi < 8; ++mi) {
      Af[mi][0] = *(const bf16x8*)(aH + (mi * 16 + fr) * 128 + cOff0);
      Af[mi][1] = *(const bf16x8*)(aH + (mi * 16 + fr) * 128 + cOff1);
    }
#pragma unroll
    for (int ni = 0; ni < 2; ++ni) {
      Bf[ni][0] = *(const bf16x8*)(bH + (bRow0 + ni * 16) * 128 + cOff0);
      Bf[ni][1] = *(const bf16x8*)(bH + (bRow0 + ni * 16) * 128 + cOff1);
    }
    PRE_MFMA();
#pragma unroll
    for (int mi = 0; mi < 8; ++mi)
#pragma unroll
      for (int ni = 0; ni < 2; ++ni) {
        acc[mi][ni] = __builtin_amdgcn_mfma_f32_16x16x32_bf16(Af[mi][0], Bf[ni][0], acc[mi][ni], 0, 0, 0);
        acc[mi][ni] = __builtin_amdgcn_mfma_f32_16x16x32_bf16(Af[mi][1], Bf[ni][1], acc[mi][ni], 0, 0, 0);
      }
    POST_MFMA();

    // ---- phase B: stage A(kt+2) (A(kt) reads retired at phase-A lgkm0+barrier);
    //      read Bf[2..3]; MFMA (ni 2..3); counted vmcnt before boundary barrier.
    if (kt + 2 < NT) { STAGE(ALDS(bsel, 0), As0 + k2); STAGE(ALDS(bsel, 1), As1 + k2); }
#pragma unroll
    for (int ni = 2; ni < 4; ++ni) {
      Bf[ni][0] = *(const bf16x8*)(bH + (bRow0 + ni * 16) * 128 + cOff0);
      Bf[ni][1] = *(const bf16x8*)(bH + (bRow0 + ni * 16) * 128 + cOff1);
    }
    PRE_MFMA();
#pragma unroll
    for (int mi = 0; mi < 8; ++mi)
#pragma unroll
      for (int ni = 2; ni < 4; ++ni) {
        acc[mi][ni] = __builtin_amdgcn_mfma_f32_16x16x32_bf16(Af[mi][0], Bf[ni][0], acc[mi][ni], 0, 0, 0);
        acc[mi][ni] = __builtin_amdgcn_mfma_f32_16x16x32_bf16(Af[mi][1], Bf[ni][1], acc[mi][ni], 0, 0, 0);
      }
    __builtin_amdgcn_s_setprio(0);
    if (kt < NT - 2)       { asm volatile("s_waitcnt vmcnt(4)" ::: "memory"); }
    else if (kt == NT - 2) { asm volatile("s_waitcnt vmcnt(0)" ::: "memory"); }
    __builtin_amdgcn_s_barrier();
    __builtin_amdgcn_sched_barrier(0);
  }

  // ---- epilogue: C[row][col] bf16; row = m0+wm*128+mi*16+fq*4+j, col = n0+wn*64+ni*16+fr
  unsigned short* Cg = Call + (long)bz * cPerB;
  const int colBase = n0 + wn * 64 + fr;
  const int rowBase = m0 + wm * 128 + fq * 4;
#pragma unroll
  for (int mi = 0; mi < 8; ++mi)
#pragma unroll
    for (int ni = 0; ni < 4; ++ni) {
      const int col = colBase + ni * 16;
      const int rw = rowBase + mi * 16;
#pragma unroll
      for (int j = 0; j < 4; ++j)
        Cg[(size_t)(rw + j) * Nn + col] = f2b(acc[mi][ni][j]);
    }

  if (STATS) {
    const int e = top1[bz];
#pragma unroll
    for (int ni = 0; ni < 4; ++ni) {
      float s1 = 0.f, s2 = 0.f;
#pragma unroll
      for (int mi = 0; mi < 8; ++mi)
#pragma unroll
        for (int j = 0; j < 4; ++j) { float v = acc[mi][ni][j]; s1 += v; s2 += v * v; }
      s1 += __shfl_xor(s1, 16); s2 += __shfl_xor(s2, 16);
      s1 += __shfl_xor(s1, 32); s2 += __shfl_xor(s2, 32);
      if (fq == 0) {
        const int col = colBase + ni * 16;
        atomicAdd(&ssum[e * Hc + col], s1);
        atomicAdd(&ssq[e * Hc + col], s2);
      }
    }
  }
#undef STAGE
#undef ALDS
#undef BLDS
}

// ---------------- BN finalize: scale/shift per [E,H] ----------------
__global__ void k_bnfin(const float* __restrict__ ssum, const float* __restrict__ ssq,
                        const int* __restrict__ top1,
                        const float* __restrict__ gamma, const float* __restrict__ beta,
                        float* __restrict__ scale, float* __restrict__ shift) {
  const int i = blockIdx.x * 256 + threadIdx.x;  // E*H = 4096
  const int e = i >> 10;
  int c = 0;
  for (int j = 0; j < Bc; ++j) c += (top1[j] == e) ? 1 : 0;
  float cf = fmaxf((float)c * (float)Nc, 1.0f);
  float mean = ssum[i] / cf;
  float var = ssq[i] / cf - mean * mean;
  float inv = rsqrtf(var + EPS);
  float sc = gamma[i] * inv;
  scale[i] = sc;
  shift[i] = beta[i] - mean * sc;
}

// ---------------- apply BN + ReLU, bf16 -> fp32 out ----------------
__global__ void k_apply(const unsigned short* __restrict__ ob,
                        const float* __restrict__ scale, const float* __restrict__ shift,
                        const int* __restrict__ top1, float* __restrict__ y) {
  size_t idx = ((size_t)blockIdx.x * 256 + threadIdx.x) * 4;
  const int b = (int)(idx >> 19);     // N*H = 2^19
  const int k = (int)(idx & 1023);    // H = 1024
  const int e = top1[b];
  us4 u = *(const us4*)(ob + idx);
  float4 sc = *(const float4*)(scale + e * Hc + k);
  float4 sh = *(const float4*)(shift + e * Hc + k);
  float4 r;
  r.x = fmaxf(fmaf(b2f(u.x), sc.x, sh.x), 0.f);
  r.y = fmaxf(fmaf(b2f(u.y), sc.y, sh.y), 0.f);
  r.z = fmaxf(fmaf(b2f(u.z), sc.z, sh.z), 0.f);
  r.w = fmaxf(fmaf(b2f(u.w), sc.w, sh.w), 0.f);
  *(float4*)(y + idx) = r;
}

extern "C" void kernel_launch(void* const* d_in, const int* in_sizes, int n_in,
                              void* d_out, int out_size, void* d_ws, size_t ws_size,
                              hipStream_t stream) {
  const float* x     = (const float*)d_in[0];
  const float* adj   = (const float*)d_in[1];
  const float* rw    = (const float*)d_in[2];
  const float* rb    = (const float*)d_in[3];
  const float* ew    = (const float*)d_in[4];
  const float* gamma = (const float*)d_in[5];
  const float* beta  = (const float*)d_in[6];
  float* out = (float*)d_out;
  char* ws = (char*)d_ws;

  // workspace layout (bytes)
  float* xm    = (float*)(ws + 0);          // 262144
  float* ssum  = (float*)(ws + 262144);     // 16384
  float* ssq   = (float*)(ws + 278528);     // 16384
  float* scale = (float*)(ws + 294912);     // 16384
  float* shift = (float*)(ws + 311296);     // 16384
  int*   top1  = (int*)  (ws + 327680);     // 256
  unsigned short* xb   = (unsigned short*)(ws + 327936);     // 67108864 (aliased by outb)
  unsigned short* adjb = (unsigned short*)(ws + 67436800);   // 33554432
  unsigned short* wT   = (unsigned short*)(ws + 100991232);  // 8388608
  unsigned short* supT = (unsigned short*)(ws + 109379840);  // 67108864
  unsigned short* outb = xb;  // x_bf16 dead after GEMM1 -> reuse for out_bf16

  hipMemsetAsync(ws, 0, 294912, stream);  // zero xm + ssum + ssq

  k_xconv<<<Bc * 16, 256, 0, stream>>>(x, xb, xm);
  k_adjconv<<<(Bc * Nc * Nc) / 1024, 256, 0, stream>>>(adj, adjb);
  k_wtrans<<<dim3(Hc / 32, Hc / 32, Ec), dim3(32, 8), 0, stream>>>(ew, wT);
  k_router<<<Bc, 256, 0, stream>>>(xm, rw, rb, top1);

  // GEMM1: supT[b][k][n] = sum_h wT[e][k][h] * x[b][n][h];  M=1024 (NX=4), Nn=512 (NY=2), K=1024
  gemm9<4, 2, false><<<512, 512, 0, stream>>>(
      wT, xb, supT, top1, nullptr, nullptr,
      Nc, Hc, 0L, (long)Nc * Hc, (long)Hc * Nc, (long)Hc * Hc);

  // GEMM2: out[b][n][k] = sum_m adj[b][n][m] * supT[b][k][m];  M=512 (NX=2), Nn=1024 (NY=4), K=512
  gemm9<2, 4, true><<<512, 512, 0, stream>>>(
      adjb, supT, outb, top1, ssum, ssq,
      Hc, Nc, (long)Nc * Nc, (long)Hc * Nc, (long)Nc * Hc, 0L);

  k_bnfin<<<(Ec * Hc) / 256, 256, 0, stream>>>(ssum, ssq, top1, gamma, beta, scale, shift);
  k_apply<<<(Bc * Nc * Hc) / 1024, 256, 0, stream>>>(outb, scale, shift, top1, out);
}

// Round 9
// 450.617 us; speedup vs baseline: 1.0245x; 1.0103x over previous
//
#include <hip/hip_runtime.h>
#include <hip/hip_bf16.h>
#include <cstdint>

// Problem constants (from reference): B=64 graphs, N=512 nodes, H=1024 hidden, E=4 experts.
constexpr int Bc = 64, Nc = 512, Hc = 1024, Ec = 4;
constexpr float EPS = 1e-5f;

typedef __attribute__((ext_vector_type(8))) short bf16x8;
typedef __attribute__((ext_vector_type(4))) float f32x4;
typedef __attribute__((ext_vector_type(4))) unsigned short us4;

__device__ __forceinline__ unsigned short f2b(float f) {
  union { float f; unsigned u; } v; v.f = f;
  unsigned r = v.u + 0x7fffu + ((v.u >> 16) & 1u);   // RNE
  return (unsigned short)(r >> 16);
}
__device__ __forceinline__ float b2f(unsigned short s) {
  union { unsigned u; float f; } v; v.u = ((unsigned)s) << 16;
  return v.f;
}

// ---------------- x: fp32 -> bf16, plus per-(b,h) sums for router mean ----------------
// grid: Bc*16 blocks, 256 thr. Block = (graph b, 32 rows); unroll 4 keeps 4 loads in flight.
__global__ void k_xconv(const float* __restrict__ x, unsigned short* __restrict__ xb,
                        float* __restrict__ xm) {
  const int b = blockIdx.x >> 4;
  const int n0 = (blockIdx.x & 15) << 5;
  const int t = threadIdx.x;
  size_t base = ((size_t)b * Nc + n0) * Hc + t * 4;
  float s0 = 0.f, s1 = 0.f, s2 = 0.f, s3 = 0.f;
#pragma unroll 4
  for (int i = 0; i < 32; ++i) {
    float4 v = *(const float4*)(x + base + (size_t)i * Hc);
    us4 u; u.x = f2b(v.x); u.y = f2b(v.y); u.z = f2b(v.z); u.w = f2b(v.w);
    *(us4*)(xb + base + (size_t)i * Hc) = u;
    s0 += v.x; s1 += v.y; s2 += v.z; s3 += v.w;
  }
  float* p = xm + b * Hc + t * 4;
  atomicAdd(p + 0, s0); atomicAdd(p + 1, s1);
  atomicAdd(p + 2, s2); atomicAdd(p + 3, s3);
}

// ---------------- adj: fp32 -> bf16 ----------------
__global__ void k_adjconv(const float* __restrict__ a, unsigned short* __restrict__ ab) {
  size_t i = ((size_t)blockIdx.x * 256 + threadIdx.x) * 4;
  float4 v = *(const float4*)(a + i);
  us4 u; u.x = f2b(v.x); u.y = f2b(v.y); u.z = f2b(v.z); u.w = f2b(v.w);
  *(us4*)(ab + i) = u;
}

// ---------------- expert_w: fp32 -> bf16 transposed: wT[e][k][h] = w[e][h][k] ----------------
__global__ void k_wtrans(const float* __restrict__ w, unsigned short* __restrict__ wT) {
  __shared__ unsigned short tile[32][33];
  const int e = blockIdx.z;
  const int bx = blockIdx.x * 32;
  const int by = blockIdx.y * 32;
  const float* W = w + (size_t)e * Hc * Hc;
  unsigned short* WT = wT + (size_t)e * Hc * Hc;
#pragma unroll
  for (int i = 0; i < 4; ++i) {
    int r = by + threadIdx.y + i * 8;
    tile[threadIdx.y + i * 8][threadIdx.x] = f2b(W[(size_t)r * Hc + bx + threadIdx.x]);
  }
  __syncthreads();
#pragma unroll
  for (int i = 0; i < 4; ++i) {
    int k = bx + threadIdx.y + i * 8;
    WT[(size_t)k * Hc + by + threadIdx.x] = tile[threadIdx.x][threadIdx.y + i * 8];
  }
}

// ---------------- router: scores + argmax ----------------
__global__ void k_router(const float* __restrict__ xm, const float* __restrict__ rw,
                         const float* __restrict__ rb, int* __restrict__ top1) {
  const int b = blockIdx.x;
  const int t = threadIdx.x;
  float sc0 = 0, sc1 = 0, sc2 = 0, sc3 = 0;
  const float inv = 1.0f / (float)Nc;
#pragma unroll
  for (int i = 0; i < 4; ++i) {
    int h = t * 4 + i;
    float v = xm[b * Hc + h] * inv;
    sc0 += v * rw[h * 4 + 0]; sc1 += v * rw[h * 4 + 1];
    sc2 += v * rw[h * 4 + 2]; sc3 += v * rw[h * 4 + 3];
  }
#pragma unroll
  for (int off = 1; off < 64; off <<= 1) {
    sc0 += __shfl_xor(sc0, off); sc1 += __shfl_xor(sc1, off);
    sc2 += __shfl_xor(sc2, off); sc3 += __shfl_xor(sc3, off);
  }
  __shared__ float red[4][4];
  const int lane = t & 63, wv = t >> 6;
  if (lane == 0) { red[wv][0] = sc0; red[wv][1] = sc1; red[wv][2] = sc2; red[wv][3] = sc3; }
  __syncthreads();
  if (t == 0) {
    float s[4];
#pragma unroll
    for (int e = 0; e < 4; ++e)
      s[e] = red[0][e] + red[1][e] + red[2][e] + red[3][e] + rb[e];
    int best = 0; float bv = s[0];
#pragma unroll
    for (int e = 1; e < 4; ++e) { if (s[e] > bv) { bv = s[e]; best = e; } }
    top1[b] = best;
  }
}

// ===== 256x256 single-barrier counted-lgkm MFMA GEMM: C[M,Nn] = A[M,K] * Bt[Nn,K]^T =====
// BM=BN=256, BK=64, 8 waves (2M x 4N), per-wave 128x64, 16x16x32 bf16 MFMA.
// Per K-tile: early-stage tile kt+1 into other dbuf (issue-to-wait ~1 tile, so the boundary
// vmcnt(0) is latency-covered); issue 24 ds_read_b128 in 3 pinned groups; counted
// lgkmcnt(12)/(4)/(0) lets R2/R3 LDS transfer hide under MFMA clusters 1-2 (DS completes
// in-order per wave). ONE s_barrier per tile. Write-after-read safety: the buffer staged at
// tile kt was read at kt-1, and every wave passed lgkmcnt(0) before the kt-1 boundary barrier.
#define GLDS16(g, l) __builtin_amdgcn_global_load_lds( \
    (__attribute__((address_space(1))) const void*)(g), \
    (__attribute__((address_space(3))) void*)(l), 16, 0, 0)

template<int NX, int NY, bool STATS>
__global__ __launch_bounds__(512, 2) void gemm10(
    const unsigned short* __restrict__ Aall, const unsigned short* __restrict__ Btall,
    unsigned short* __restrict__ Call, const int* __restrict__ top1,
    float* __restrict__ ssum, float* __restrict__ ssq,
    int Nn, int K, long aPerB, long btPerB, long cPerB, long aExp)
{
  static_assert(NX * NY == 8, "grid per graph must be 8 blocks");
  __shared__ char Lds[131072];
#define ALDS(b, h) (Lds + (b) * 65536 + (h) * 16384)
#define BLDS(b, h) (Lds + (b) * 65536 + 32768 + (h) * 16384)

  const int tid = threadIdx.x;
  const int w = tid >> 6, lane = tid & 63;
  const int wm = w >> 2, wn = w & 3;
  const int fr = lane & 15, fq = lane >> 4;

  // XCD-aware bijective block swizzle: 64 consecutive blocks (8 graphs) per XCD chunk.
  const int id = blockIdx.x;
  const int s = (id & 7) * (NX * NY * 8) + (id >> 3);
  const int bz = s >> 3;
  const int r = s & 7;
  const int bx = r % NX, by = r / NX;
  const int m0 = bx * 256, n0 = by * 256;

  const unsigned short* Ag = Aall + (aExp ? (long)top1[bz] * aExp : (long)bz * aPerB);
  const unsigned short* Bg = Btall + (long)bz * btPerB;

  const unsigned short* As0 = Ag + (size_t)m0 * K;
  const unsigned short* As1 = Ag + (size_t)(m0 + 128) * K;
  const unsigned short* Bs0 = Bg + (size_t)n0 * K;
  const unsigned short* Bs1 = Bg + (size_t)(n0 + 128) * K;

  // staging: thread t covers lds 16B-chunks c=tid and c=tid+512 of a 128x64 half-tile
  // (row = c>>3, lds-chunk = c&7). Global source chunk pre-swizzled: g = (c&7)^(row&7)
  // so that lds(row, cc) holds global chunk cc^(row&7)  [both-sides swizzle].
  const int rowA = tid >> 3;                       // 0..63 (2nd GLDS16 covers rowA+64; same &7)
  const int g8 = ((tid & 7) ^ (rowA & 7)) * 8;     // element offset within BK
  const int wb = w << 10;                          // wave-uniform LDS base (w*64*16B)
#define STAGE(slot, src) do { \
    GLDS16((src) + (size_t)rowA * K + g8, (slot) + wb); \
    GLDS16((src) + (size_t)(rowA + 64) * K + g8, (slot) + wb + 8192); \
  } while (0)

  // fragment read addressing: logical chunk kc at byte row*128 + (kc^(row&7))*16
  const int cOff0 = ((fq ^ (fr & 7)) * 16);
  const int cOff1 = cOff0 ^ 64;
  const int bRow0 = (wn & 1) * 64 + fr;            // B row within half (row&7 == fr&7)

  f32x4 acc[8][4] = {};
  const int NT = K >> 6;

  // ---- prologue: stage tile 0 (both A halves + both B halves); drain; sync
  STAGE(ALDS(0, 0), As0);
  STAGE(ALDS(0, 1), As1);
  STAGE(BLDS(0, 0), Bs0);
  STAGE(BLDS(0, 1), Bs1);
  asm volatile("s_waitcnt vmcnt(0)" ::: "memory");
  __builtin_amdgcn_s_barrier();
  __builtin_amdgcn_sched_barrier(0);

  for (int kt = 0; kt < NT; ++kt) {
    const int bsel = kt & 1;
    const int b1 = bsel ^ 1;
    // ---- early stage of tile kt+1 into b1 (read at kt-1; safe after boundary barrier)
    if (kt + 1 < NT) {
      const int k1 = (kt + 1) << 6;
      STAGE(ALDS(b1, 0), As0 + k1);
      STAGE(ALDS(b1, 1), As1 + k1);
      STAGE(BLDS(b1, 0), Bs0 + k1);
      STAGE(BLDS(b1, 1), Bs1 + k1);
    }
    __builtin_amdgcn_sched_barrier(0);

    const char* aH = ALDS(bsel, wm);
    const char* bH = BLDS(bsel, wn >> 1);
    bf16x8 Af[8][2]; bf16x8 Bf[4][2];

    // ---- R1 (12 ds_read_b128): Af[0..3] + Bf[0..1]
#pragma unroll
    for (int mi = 0; mi < 4; ++mi) {
      Af[mi][0] = *(const bf16x8*)(aH + (mi * 16 + fr) * 128 + cOff0);
      Af[mi][1] = *(const bf16x8*)(aH + (mi * 16 + fr) * 128 + cOff1);
    }
#pragma unroll
    for (int ni = 0; ni < 2; ++ni) {
      Bf[ni][0] = *(const bf16x8*)(bH + (bRow0 + ni * 16) * 128 + cOff0);
      Bf[ni][1] = *(const bf16x8*)(bH + (bRow0 + ni * 16) * 128 + cOff1);
    }
    __builtin_amdgcn_sched_barrier(0);
    // ---- R2 (8): Af[4..7]
#pragma unroll
    for (int mi = 4; mi < 8; ++mi) {
      Af[mi][0] = *(const bf16x8*)(aH + (mi * 16 + fr) * 128 + cOff0);
      Af[mi][1] = *(const bf16x8*)(aH + (mi * 16 + fr) * 128 + cOff1);
    }
    __builtin_amdgcn_sched_barrier(0);
    // ---- R3 (4): Bf[2..3]
#pragma unroll
    for (int ni = 2; ni < 4; ++ni) {
      Bf[ni][0] = *(const bf16x8*)(bH + (bRow0 + ni * 16) * 128 + cOff0);
      Bf[ni][1] = *(const bf16x8*)(bH + (bRow0 + ni * 16) * 128 + cOff1);
    }
    __builtin_amdgcn_sched_barrier(0);

    // ---- cluster 1: needs R1 (12 oldest done; R2+R3 = 12 may remain)
    asm volatile("s_waitcnt lgkmcnt(12)" ::: "memory");
    __builtin_amdgcn_sched_barrier(0);
    __builtin_amdgcn_s_setprio(1);
#pragma unroll
    for (int mi = 0; mi < 4; ++mi)
#pragma unroll
      for (int ni = 0; ni < 2; ++ni) {
        acc[mi][ni] = __builtin_amdgcn_mfma_f32_16x16x32_bf16(Af[mi][0], Bf[ni][0], acc[mi][ni], 0, 0, 0);
        acc[mi][ni] = __builtin_amdgcn_mfma_f32_16x16x32_bf16(Af[mi][1], Bf[ni][1], acc[mi][ni], 0, 0, 0);
      }
    __builtin_amdgcn_sched_barrier(0);
    // ---- cluster 2: needs R2 (<=4 outstanding leaves only R3)
    asm volatile("s_waitcnt lgkmcnt(4)" ::: "memory");
    __builtin_amdgcn_sched_barrier(0);
#pragma unroll
    for (int mi = 4; mi < 8; ++mi)
#pragma unroll
      for (int ni = 0; ni < 2; ++ni) {
        acc[mi][ni] = __builtin_amdgcn_mfma_f32_16x16x32_bf16(Af[mi][0], Bf[ni][0], acc[mi][ni], 0, 0, 0);
        acc[mi][ni] = __builtin_amdgcn_mfma_f32_16x16x32_bf16(Af[mi][1], Bf[ni][1], acc[mi][ni], 0, 0, 0);
      }
    __builtin_amdgcn_sched_barrier(0);
    // ---- clusters 3+4: needs R3
    asm volatile("s_waitcnt lgkmcnt(0)" ::: "memory");
    __builtin_amdgcn_sched_barrier(0);
#pragma unroll
    for (int mi = 0; mi < 8; ++mi)
#pragma unroll
      for (int ni = 2; ni < 4; ++ni) {
        acc[mi][ni] = __builtin_amdgcn_mfma_f32_16x16x32_bf16(Af[mi][0], Bf[ni][0], acc[mi][ni], 0, 0, 0);
        acc[mi][ni] = __builtin_amdgcn_mfma_f32_16x16x32_bf16(Af[mi][1], Bf[ni][1], acc[mi][ni], 0, 0, 0);
      }
    __builtin_amdgcn_s_setprio(0);

    // ---- boundary: drain staging (issued ~1 tile ago -> latency-covered) + ONE barrier
    if (kt < NT - 1) {
      asm volatile("s_waitcnt vmcnt(0)" ::: "memory");
      __builtin_amdgcn_s_barrier();
      __builtin_amdgcn_sched_barrier(0);
    }
  }

  // ---- epilogue: C[row][col] bf16; row = m0+wm*128+mi*16+fq*4+j, col = n0+wn*64+ni*16+fr
  unsigned short* Cg = Call + (long)bz * cPerB;
  const int colBase = n0 + wn * 64 + fr;
  const int rowBase = m0 + wm * 128 + fq * 4;
#pragma unroll
  for (int mi = 0; mi < 8; ++mi)
#pragma unroll
    for (int ni = 0; ni < 4; ++ni) {
      const int col = colBase + ni * 16;
      const int rw = rowBase + mi * 16;
#pragma unroll
      for (int j = 0; j < 4; ++j)
        Cg[(size_t)(rw + j) * Nn + col] = f2b(acc[mi][ni][j]);
    }

  if (STATS) {
    const int e = top1[bz];
#pragma unroll
    for (int ni = 0; ni < 4; ++ni) {
      float s1 = 0.f, s2 = 0.f;
#pragma unroll
      for (int mi = 0; mi < 8; ++mi)
#pragma unroll
        for (int j = 0; j < 4; ++j) { float v = acc[mi][ni][j]; s1 += v; s2 += v * v; }
      s1 += __shfl_xor(s1, 16); s2 += __shfl_xor(s2, 16);
      s1 += __shfl_xor(s1, 32); s2 += __shfl_xor(s2, 32);
      if (fq == 0) {
        const int col = colBase + ni * 16;
        atomicAdd(&ssum[e * Hc + col], s1);
        atomicAdd(&ssq[e * Hc + col], s2);
      }
    }
  }
#undef STAGE
#undef ALDS
#undef BLDS
}

// ---------------- BN finalize: scale/shift per [E,H] ----------------
__global__ void k_bnfin(const float* __restrict__ ssum, const float* __restrict__ ssq,
                        const int* __restrict__ top1,
                        const float* __restrict__ gamma, const float* __restrict__ beta,
                        float* __restrict__ scale, float* __restrict__ shift) {
  const int i = blockIdx.x * 256 + threadIdx.x;  // E*H = 4096
  const int e = i >> 10;
  int c = 0;
  for (int j = 0; j < Bc; ++j) c += (top1[j] == e) ? 1 : 0;
  float cf = fmaxf((float)c * (float)Nc, 1.0f);
  float mean = ssum[i] / cf;
  float var = ssq[i] / cf - mean * mean;
  float inv = rsqrtf(var + EPS);
  float sc = gamma[i] * inv;
  scale[i] = sc;
  shift[i] = beta[i] - mean * sc;
}

// ---------------- apply BN + ReLU, bf16 -> fp32 out ----------------
__global__ void k_apply(const unsigned short* __restrict__ ob,
                        const float* __restrict__ scale, const float* __restrict__ shift,
                        const int* __restrict__ top1, float* __restrict__ y) {
  size_t idx = ((size_t)blockIdx.x * 256 + threadIdx.x) * 4;
  const int b = (int)(idx >> 19);     // N*H = 2^19
  const int k = (int)(idx & 1023);    // H = 1024
  const int e = top1[b];
  us4 u = *(const us4*)(ob + idx);
  float4 sc = *(const float4*)(scale + e * Hc + k);
  float4 sh = *(const float4*)(shift + e * Hc + k);
  float4 r;
  r.x = fmaxf(fmaf(b2f(u.x), sc.x, sh.x), 0.f);
  r.y = fmaxf(fmaf(b2f(u.y), sc.y, sh.y), 0.f);
  r.z = fmaxf(fmaf(b2f(u.z), sc.z, sh.z), 0.f);
  r.w = fmaxf(fmaf(b2f(u.w), sc.w, sh.w), 0.f);
  *(float4*)(y + idx) = r;
}

extern "C" void kernel_launch(void* const* d_in, const int* in_sizes, int n_in,
                              void* d_out, int out_size, void* d_ws, size_t ws_size,
                              hipStream_t stream) {
  const float* x     = (const float*)d_in[0];
  const float* adj   = (const float*)d_in[1];
  const float* rw    = (const float*)d_in[2];
  const float* rb    = (const float*)d_in[3];
  const float* ew    = (const float*)d_in[4];
  const float* gamma = (const float*)d_in[5];
  const float* beta  = (const float*)d_in[6];
  float* out = (float*)d_out;
  char* ws = (char*)d_ws;

  // workspace layout (bytes)
  float* xm    = (float*)(ws + 0);          // 262144
  float* ssum  = (float*)(ws + 262144);     // 16384
  float* ssq   = (float*)(ws + 278528);     // 16384
  float* scale = (float*)(ws + 294912);     // 16384
  float* shift = (float*)(ws + 311296);     // 16384
  int*   top1  = (int*)  (ws + 327680);     // 256
  unsigned short* xb   = (unsigned short*)(ws + 327936);     // 67108864 (aliased by outb)
  unsigned short* adjb = (unsigned short*)(ws + 67436800);   // 33554432
  unsigned short* wT   = (unsigned short*)(ws + 100991232);  // 8388608
  unsigned short* supT = (unsigned short*)(ws + 109379840);  // 67108864
  unsigned short* outb = xb;  // x_bf16 dead after GEMM1 -> reuse for out_bf16

  hipMemsetAsync(ws, 0, 294912, stream);  // zero xm + ssum + ssq

  k_xconv<<<Bc * 16, 256, 0, stream>>>(x, xb, xm);
  k_adjconv<<<(Bc * Nc * Nc) / 1024, 256, 0, stream>>>(adj, adjb);
  k_wtrans<<<dim3(Hc / 32, Hc / 32, Ec), dim3(32, 8), 0, stream>>>(ew, wT);
  k_router<<<Bc, 256, 0, stream>>>(xm, rw, rb, top1);

  // GEMM1: supT[b][k][n] = sum_h wT[e][k][h] * x[b][n][h];  M=1024 (NX=4), Nn=512 (NY=2), K=1024
  gemm10<4, 2, false><<<512, 512, 0, stream>>>(
      wT, xb, supT, top1, nullptr, nullptr,
      Nc, Hc, 0L, (long)Nc * Hc, (long)Hc * Nc, (long)Hc * Hc);

  // GEMM2: out[b][n][k] = sum_m adj[b][n][m] * supT[b][k][m];  M=512 (NX=2), Nn=1024 (NY=4), K=512
  gemm10<2, 4, true><<<512, 512, 0, stream>>>(
      adjb, supT, outb, top1, ssum, ssq,
      Hc, Nc, (long)Nc * Nc, (long)Hc * Nc, (long)Nc * Hc, 0L);

  k_bnfin<<<(Ec * Hc) / 256, 256, 0, stream>>>(ssum, ssq, top1, gamma, beta, scale, shift);
  k_apply<<<(Bc * Nc * Hc) / 1024, 256, 0, stream>>>(outb, scale, shift, top1, out);
}